// Round 2
// baseline (547.872 us; speedup 1.0000x reference)
//
#include <hip/hip_runtime.h>
#include <hip/hip_cooperative_groups.h>
#include <cstdint>
#include <cstddef>

namespace cg = cooperative_groups;

#define NN    8192
#define DIN   256
#define DOUT  128
#define LRA   0.2f
#define RPB   16      // rows per block
#define NB    512     // blocks (512 x 16 = 8192 rows); 2 blocks/CU co-resident

// One cooperative kernel, phases separated by grid.sync():
//  P1: h = input@W  (block computes its own 16 rows; input tile in LDS)
//  P2: s,t from the P1 accumulator registers (shuffle+LDS reduce) -> global
//  --- grid.sync #1 ---
//  P3: stage t into LDS; counting-rank-sort of this block's 16 t's -> order
//  --- grid.sync #2 ---
//  P4: per row: masked-softmax denom (one coalesced int4 pass over adj row),
//      sorted-t walk for top-(action+1) threshold, sparse gather of h, ELU.
__global__ __launch_bounds__(256, 2) void gat_fused_kernel(
    const float* __restrict__ input, const int* __restrict__ adj,
    const int* __restrict__ action, const float* __restrict__ W,
    const float* __restrict__ a_self, const float* __restrict__ a_neighs,
    const int* __restrict__ policy, float* __restrict__ out,
    float* __restrict__ h, float* __restrict__ s_arr,
    float* __restrict__ t_arr, int* __restrict__ order)
{
    cg::grid_group grid = cg::this_grid();

    __shared__ union {
        float tile[RPB][DIN];  // 16 KB, P1 only
        float tl[NN];          // 32 KB, P3/P4
    } u;
    __shared__ float red[4];
    __shared__ float numlds[2][DOUT];
    __shared__ float pr[4][16];      // P2 per-wave partials (8 rows x {s,t})
    __shared__ int   prank[4][RPB];  // P3 per-wave rank partials
    __shared__ int   sel_j[64];
    __shared__ float sel_w[64];
    __shared__ int   sel_cnt_sh;
    __shared__ int   done_sh;

    const int tid  = threadIdx.x;
    const int row0 = blockIdx.x * RPB;
    const int c    = tid & 127;
    const int g    = tid >> 7;       // 0..1
    const int lane = tid & 63;
    const int wave = tid >> 6;       // 0..3

    // ---------------- P1: h rows [row0, row0+16) ----------------
    {
        const float4* in4 = (const float4*)(input + (size_t)row0 * DIN);
        float4* t4 = (float4*)&u.tile[0][0];
        #pragma unroll
        for (int k = 0; k < 4; ++k) t4[tid + k * 256] = in4[tid + k * 256];
    }
    __syncthreads();
    {
        float acc[8];
        #pragma unroll
        for (int m = 0; m < 8; ++m) acc[m] = 0.f;
        for (int k = 0; k < DIN; k += 4) {
            const float w0 = W[(k + 0) * DOUT + c];
            const float w1 = W[(k + 1) * DOUT + c];
            const float w2 = W[(k + 2) * DOUT + c];
            const float w3 = W[(k + 3) * DOUT + c];
            #pragma unroll
            for (int m = 0; m < 8; ++m) {
                const float4 av = *(const float4*)&u.tile[g * 8 + m][k];
                acc[m] += av.x * w0 + av.y * w1 + av.z * w2 + av.w * w3;
            }
        }
        #pragma unroll
        for (int m = 0; m < 8; ++m)
            h[(size_t)(row0 + g * 8 + m) * DOUT + c] = acc[m];

        // ---------------- P2: s,t from acc registers ----------------
        const float as = a_self[c];
        const float an = a_neighs[c];
        #pragma unroll
        for (int m = 0; m < 8; ++m) {
            float vs = acc[m] * as;
            float vt = acc[m] * an;
            for (int off = 32; off > 0; off >>= 1) {
                vs += __shfl_down(vs, off);
                vt += __shfl_down(vt, off);
            }
            if (lane == 0) { pr[wave][2 * m] = vs; pr[wave][2 * m + 1] = vt; }
        }
    }
    __syncthreads();
    if (tid < 16) {
        const int m  = tid & 7;
        const int gg = tid >> 3;
        const int r  = row0 + gg * 8 + m;
        s_arr[r] = pr[2 * gg][2 * m]     + pr[2 * gg + 1][2 * m];
        t_arr[r] = pr[2 * gg][2 * m + 1] + pr[2 * gg + 1][2 * m + 1];
    }
    grid.sync();   // all of t_arr, s_arr, h visible

    // ---------------- P3: stage t, rank this block's 16 j's ----------------
    {
        const float4* t4 = (const float4*)t_arr;
        float4* tl4 = (float4*)u.tl;
        #pragma unroll
        for (int k = 0; k < 8; ++k) tl4[tid + k * 256] = t4[tid + k * 256];
    }
    __syncthreads();
    {
        float tj[RPB];
        int   r[RPB];
        #pragma unroll
        for (int q = 0; q < RPB; ++q) { tj[q] = u.tl[row0 + q]; r[q] = 0; }
        const int kbase = tid * 32;
        for (int it = 0; it < 32; ++it) {
            const int k = kbase + ((it + tid) & 31);   // bank-conflict-free
            const float tk = u.tl[k];
            #pragma unroll
            for (int q = 0; q < RPB; ++q)
                r[q] += (tk > tj[q] || (tk == tj[q] && k < row0 + q)) ? 1 : 0;
        }
        #pragma unroll
        for (int q = 0; q < RPB; ++q) {
            int v = r[q];
            for (int off = 32; off > 0; off >>= 1) v += __shfl_down(v, off);
            if (lane == 0) prank[wave][q] = v;
        }
        __syncthreads();
        if (tid < RPB) {
            const int rr = prank[0][tid] + prank[1][tid] +
                           prank[2][tid] + prank[3][tid];
            order[rr] = row0 + tid;   // descending rank -> index
        }
    }
    grid.sync();   // order complete everywhere

    // ---------------- P4: per-row softmax-denom + threshold + gather ----------------
    const int policyv = policy[0];
    const float tmax  = u.tl[order[0]];
    const float4* tl4c = (const float4*)u.tl;

    for (int rr = 0; rr < RPB; ++rr) {
        const int row = row0 + rr;
        const float s  = s_arr[row];
        const float zc = s + tmax;
        const float C  = fmaxf(zc, LRA * zc);   // lrelu(s+tmax) >= every e

        // denominator: one coalesced int4 pass over the adj row
        const int4* arow = (const int4*)(adj + (size_t)row * NN);
        float acc = 0.f;
        #pragma unroll
        for (int k = 0; k < 8; ++k) {
            const int idx = tid + k * 256;
            const int4   a  = arow[idx];
            const float4 tv = tl4c[idx];
            float z, e;
            z = s + tv.x; e = fmaxf(z, LRA * z); if (a.x > 0) acc += __expf(e - C);
            z = s + tv.y; e = fmaxf(z, LRA * z); if (a.y > 0) acc += __expf(e - C);
            z = s + tv.z; e = fmaxf(z, LRA * z); if (a.z > 0) acc += __expf(e - C);
            z = s + tv.w; e = fmaxf(z, LRA * z); if (a.w > 0) acc += __expf(e - C);
        }
        for (int off = 32; off > 0; off >>= 1) acc += __shfl_down(acc, off);
        if (lane == 0) red[wave] = acc;
        __syncthreads();
        const float l = red[0] + red[1] + red[2] + red[3];

        // walk sorted-t order with wave 0: find threshold, compact selected
        int K = action[row] + 1;
        if (policyv == 0) K = 0x7FFFFFFF;
        float accv = 0.f;
        float tthr = -3.0e38f;
        int found = 0, cnt = 0, base = 0;

        while (true) {
            if (tid < 64) {
                const int p = base + lane;
                int j = 0, valid = 0;
                float tjv = -3.0e38f;
                if (p < NN) {
                    j     = order[p];
                    tjv   = u.tl[j];
                    valid = (adj[(size_t)row * NN + j] > 0) ? 1 : 0;
                }
                const unsigned long long vm = __ballot(valid);
                if (!found) {
                    const int cv = __popcll(vm);
                    if (cnt + cv >= K) {
                        const int need = K - cnt;
                        const int myrank =
                            __popcll(vm & ((1ull << lane) - 1ull)) + 1;
                        const unsigned long long pm =
                            __ballot(valid && (myrank == need));
                        const int L = __ffsll((long long)pm) - 1;
                        tthr  = __shfl(tjv, L);
                        found = 1;
                    } else {
                        cnt += cv;
                    }
                }
                const int selected = valid && (tjv >= tthr);
                const unsigned long long sm = __ballot(selected);
                const int pos = __popcll(sm & ((1ull << lane) - 1ull));
                if (selected) {
                    const float z = s + tjv;
                    const float e = fmaxf(z, LRA * z);
                    sel_j[pos] = j;
                    sel_w[pos] = __expf(e - C);
                }
                if (lane == 0) {
                    sel_cnt_sh = __popcll(sm);
                    const int nb = base + 64;
                    int dn;
                    if (nb >= NN)   dn = 1;
                    else if (found) dn = (u.tl[order[nb]] < tthr) ? 1 : 0;
                    else            dn = 0;
                    done_sh = dn;
                }
            }
            __syncthreads();
            const int nsel = sel_cnt_sh;
            const int dn   = done_sh;
            for (int e2 = g; e2 < nsel; e2 += 2)
                accv += sel_w[e2] * h[(size_t)sel_j[e2] * DOUT + c];
            base += 64;
            if (dn) break;
            __syncthreads();
        }

        numlds[g][c] = accv;
        __syncthreads();
        if (tid < 128) {
            const float v = (numlds[0][tid] + numlds[1][tid]) / l;
            out[(size_t)row * DOUT + tid] = (v > 0.f) ? v : expm1f(v);
        }
        __syncthreads();   // protect red/sel/numlds before next row
    }
}

// ---------------------------------------------------------------------------
extern "C" void kernel_launch(void* const* d_in, const int* in_sizes, int n_in,
                              void* d_out, int out_size, void* d_ws,
                              size_t ws_size, hipStream_t stream)
{
    const float* input    = (const float*)d_in[0];
    const int*   adj      = (const int*)d_in[1];
    const int*   action   = (const int*)d_in[2];
    const float* W        = (const float*)d_in[3];
    const float* a_self   = (const float*)d_in[4];
    const float* a_neighs = (const float*)d_in[5];
    const int*   policy   = (const int*)d_in[6];
    float* out = (float*)d_out;

    float* ws    = (float*)d_ws;
    float* h     = ws;                          // 8192*128 fp32 = 4 MB
    float* s     = ws + (size_t)NN * DOUT;      // 8192 fp32
    float* t     = s + NN;                      // 8192 fp32
    int*   order = (int*)(t + NN);              // 8192 int32

    void* args[] = { (void*)&input, (void*)&adj, (void*)&action, (void*)&W,
                     (void*)&a_self, (void*)&a_neighs, (void*)&policy,
                     (void*)&out, (void*)&h, (void*)&s, (void*)&t,
                     (void*)&order };
    hipLaunchCooperativeKernel((const void*)gat_fused_kernel, dim3(NB),
                               dim3(256), args, 0, stream);
}

// Round 3
// 456.271 us; speedup vs baseline: 1.2008x; 1.2008x over previous
//
#include <hip/hip_runtime.h>
#include <cstdint>
#include <cstddef>

#define NN    8192
#define DIN   256
#define DOUT  128
#define LRA   0.2f

// ---------------------------------------------------------------------------
// K1: h = input@W  +  s,t computed straight from the accumulator registers.
// 512 blocks x 256 threads; 16 rows/block; input tile in LDS; W from L2.
// ---------------------------------------------------------------------------
__global__ __launch_bounds__(256) void gemm_st_kernel(
    const float* __restrict__ input, const float* __restrict__ W,
    const float* __restrict__ a_self, const float* __restrict__ a_neighs,
    float* __restrict__ h, float* __restrict__ s_arr,
    float* __restrict__ t_arr)
{
    __shared__ float tile[16][DIN];   // 16 KB
    __shared__ float pr[4][16];       // per-wave {s,t} partials for 8 rows
    const int tid  = threadIdx.x;
    const int row0 = blockIdx.x * 16;
    {
        const float4* in4 = (const float4*)(input + (size_t)row0 * DIN);
        float4* t4 = (float4*)&tile[0][0];
        #pragma unroll
        for (int k = 0; k < 4; ++k) t4[tid + k * 256] = in4[tid + k * 256];
    }
    __syncthreads();
    const int c    = tid & 127;
    const int g    = tid >> 7;        // 0..1
    const int lane = tid & 63;
    const int wave = tid >> 6;        // 0..3
    float acc[8];
    #pragma unroll
    for (int m = 0; m < 8; ++m) acc[m] = 0.f;
    for (int k = 0; k < DIN; k += 4) {
        const float w0 = W[(k + 0) * DOUT + c];
        const float w1 = W[(k + 1) * DOUT + c];
        const float w2 = W[(k + 2) * DOUT + c];
        const float w3 = W[(k + 3) * DOUT + c];
        #pragma unroll
        for (int m = 0; m < 8; ++m) {
            const float4 av = *(const float4*)&tile[g * 8 + m][k];
            acc[m] += av.x * w0 + av.y * w1 + av.z * w2 + av.w * w3;
        }
    }
    #pragma unroll
    for (int m = 0; m < 8; ++m)
        h[(size_t)(row0 + g * 8 + m) * DOUT + c] = acc[m];

    const float as = a_self[c];
    const float an = a_neighs[c];
    #pragma unroll
    for (int m = 0; m < 8; ++m) {
        float vs = acc[m] * as;
        float vt = acc[m] * an;
        for (int off = 32; off > 0; off >>= 1) {
            vs += __shfl_down(vs, off);
            vt += __shfl_down(vt, off);
        }
        if (lane == 0) { pr[wave][2 * m] = vs; pr[wave][2 * m + 1] = vt; }
    }
    __syncthreads();
    if (tid < 16) {
        const int m  = tid & 7;
        const int gg = tid >> 3;
        const int r  = row0 + gg * 8 + m;
        s_arr[r] = pr[2 * gg][2 * m]     + pr[2 * gg + 1][2 * m];
        t_arr[r] = pr[2 * gg][2 * m + 1] + pr[2 * gg + 1][2 * m + 1];
    }
}

// ---------------------------------------------------------------------------
// K2: descending rank of t by counting; emits order[rank]=j AND
// tsorted[rank]=t[j] so the walk in K3 reads sorted values coalesced.
// 256 blocks x 256 threads; per-seg bank rotation kills the 8-way conflict.
// ---------------------------------------------------------------------------
__global__ __launch_bounds__(256) void rank_kernel(
    const float* __restrict__ t, int* __restrict__ order,
    float* __restrict__ tsorted)
{
    __shared__ float tl[NN];        // 32 KB
    __shared__ int   part[8][32];
    for (int k = threadIdx.x; k < NN; k += 256) tl[k] = t[k];
    __syncthreads();
    const int jloc = threadIdx.x & 31;
    const int seg  = threadIdx.x >> 5;
    const int j    = blockIdx.x * 32 + jloc;
    const float tj = tl[j];
    int r = 0;
    const int k0 = seg * (NN / 8);
    for (int i = 0; i < NN / 8; ++i) {
        const int k = k0 + ((i + seg * 4) & (NN / 8 - 1));  // bank-rotated
        const float tk = tl[k];
        r += (tk > tj || (tk == tj && k < j)) ? 1 : 0;
    }
    part[seg][jloc] = r;
    __syncthreads();
    if (threadIdx.x < 32) {
        int rr = 0;
        #pragma unroll
        for (int ss = 0; ss < 8; ++ss) rr += part[ss][threadIdx.x];
        const int jj = blockIdx.x * 32 + threadIdx.x;
        order[rr]   = jj;
        tsorted[rr] = tl[jj];
    }
}

// ---------------------------------------------------------------------------
// K3: one block per row (8192 blocks). No big LDS staging -> 8 blocks/CU.
//  a) denominator: coalesced int4 adj stream + float4 t (L2-hot)
//  b) wave-0 sorted walk for the top-(action+1) threshold (tsorted coalesced)
//  c) gather: 8 selected h-rows concurrently (32 thr x float4 each)
// ---------------------------------------------------------------------------
__global__ __launch_bounds__(256, 8) void gat_row_kernel(
    const int* __restrict__ adj, const float* __restrict__ s_arr,
    const float* __restrict__ t_arr, const int* __restrict__ order,
    const float* __restrict__ tsorted, const int* __restrict__ action,
    const float* __restrict__ h, const int* __restrict__ policy,
    float* __restrict__ out)
{
    __shared__ float red[4];
    __shared__ float numlds[8][DOUT];   // 4 KB
    __shared__ int   sel_j[64];
    __shared__ float sel_w[64];
    __shared__ int   sel_cnt_sh;
    __shared__ int   done_sh;

    const int row  = blockIdx.x;
    const int tid  = threadIdx.x;
    const int lane = tid & 63;
    const int wave = tid >> 6;

    const float s    = s_arr[row];
    const float tmax = tsorted[0];
    const float zc   = s + tmax;
    const float C    = fmaxf(zc, LRA * zc);   // lrelu(s+tmax) >= every e

    // ---- a) denominator ----
    const int4*   arow = (const int4*)(adj + (size_t)row * NN);
    const float4* t4   = (const float4*)t_arr;
    float acc = 0.f;
    #pragma unroll 4
    for (int k = 0; k < 8; ++k) {
        const int idx = tid + k * 256;
        const int4   a  = arow[idx];
        const float4 tv = t4[idx];
        float z, e;
        z = s + tv.x; e = fmaxf(z, LRA * z); if (a.x > 0) acc += __expf(e - C);
        z = s + tv.y; e = fmaxf(z, LRA * z); if (a.y > 0) acc += __expf(e - C);
        z = s + tv.z; e = fmaxf(z, LRA * z); if (a.z > 0) acc += __expf(e - C);
        z = s + tv.w; e = fmaxf(z, LRA * z); if (a.w > 0) acc += __expf(e - C);
    }
    for (int off = 32; off > 0; off >>= 1) acc += __shfl_down(acc, off);
    if (lane == 0) red[wave] = acc;
    __syncthreads();
    const float l = red[0] + red[1] + red[2] + red[3];

    // ---- b)+c) walk + gather ----
    int K = action[row] + 1;
    if (policy[0] == 0) K = 0x7FFFFFFF;
    const int ee = tid >> 5;           // 0..7: which selected entry
    const int c4 = tid & 31;           // float4 index within the h row
    float4 acc4 = make_float4(0.f, 0.f, 0.f, 0.f);
    float tthr = -3.0e38f;
    int found = 0, cnt = 0, base = 0;

    while (true) {
        if (tid < 64) {
            const int p = base + lane;
            int j = 0, valid = 0;
            float tjv = -3.0e38f;
            if (p < NN) {
                j     = order[p];
                tjv   = tsorted[p];
                valid = (adj[(size_t)row * NN + j] > 0) ? 1 : 0;
            }
            const unsigned long long vm = __ballot(valid);
            if (!found) {
                const int cv = __popcll(vm);
                if (cnt + cv >= K) {
                    const int need = K - cnt;
                    const int myrank =
                        __popcll(vm & ((1ull << lane) - 1ull)) + 1;
                    const unsigned long long pm =
                        __ballot(valid && (myrank == need));
                    const int L = __ffsll((long long)pm) - 1;
                    tthr  = __shfl(tjv, L);
                    found = 1;
                } else {
                    cnt += cv;
                }
            }
            const int selected = valid && (tjv >= tthr);
            const unsigned long long sm = __ballot(selected);
            const int pos = __popcll(sm & ((1ull << lane) - 1ull));
            if (selected) {
                const float z = s + tjv;
                const float e = fmaxf(z, LRA * z);
                sel_j[pos] = j;
                sel_w[pos] = __expf(e - C);
            }
            if (lane == 0) {
                sel_cnt_sh = __popcll(sm);
                const int nb = base + 64;
                int dn;
                if (nb >= NN)   dn = 1;
                else if (found) dn = (tsorted[nb] < tthr) ? 1 : 0;
                else            dn = 0;
                done_sh = dn;
            }
        }
        __syncthreads();
        const int nsel = sel_cnt_sh;
        const int dn   = done_sh;
        for (int e2 = ee; e2 < nsel; e2 += 8) {
            const float w = sel_w[e2];
            const float4 hv =
                *(const float4*)&h[(size_t)sel_j[e2] * DOUT + c4 * 4];
            acc4.x += w * hv.x; acc4.y += w * hv.y;
            acc4.z += w * hv.z; acc4.w += w * hv.w;
        }
        base += 64;
        if (dn) break;
        __syncthreads();
    }

    *(float4*)&numlds[ee][c4 * 4] = acc4;
    __syncthreads();
    if (tid < DOUT) {
        float v = 0.f;
        #pragma unroll
        for (int q = 0; q < 8; ++q) v += numlds[q][tid];
        v /= l;
        out[(size_t)row * DOUT + tid] = (v > 0.f) ? v : expm1f(v);
    }
}

// ---------------------------------------------------------------------------
extern "C" void kernel_launch(void* const* d_in, const int* in_sizes, int n_in,
                              void* d_out, int out_size, void* d_ws,
                              size_t ws_size, hipStream_t stream)
{
    const float* input    = (const float*)d_in[0];
    const int*   adj      = (const int*)d_in[1];
    const int*   action   = (const int*)d_in[2];
    const float* W        = (const float*)d_in[3];
    const float* a_self   = (const float*)d_in[4];
    const float* a_neighs = (const float*)d_in[5];
    const int*   policy   = (const int*)d_in[6];
    float* out = (float*)d_out;

    float* ws      = (float*)d_ws;
    float* h       = ws;                        // 8192*128 fp32 = 4 MB
    float* s       = ws + (size_t)NN * DOUT;    // 8192 fp32
    float* t       = s + NN;                    // 8192 fp32
    float* tsorted = t + NN;                    // 8192 fp32
    int*   order   = (int*)(tsorted + NN);      // 8192 int32

    hipLaunchKernelGGL(gemm_st_kernel, dim3(512), dim3(256), 0, stream,
                       input, W, a_self, a_neighs, h, s, t);
    hipLaunchKernelGGL(rank_kernel, dim3(256), dim3(256), 0, stream,
                       t, order, tsorted);
    hipLaunchKernelGGL(gat_row_kernel, dim3(NN), dim3(256), 0, stream,
                       adj, s, t, order, tsorted, action, h, policy, out);
}